// Round 4
// baseline (224.756 us; speedup 1.0000x reference)
//
#include <hip/hip_runtime.h>

// PaddedToSegments: batched stream compaction — fused; plain cached load/store.
//   inputs: [B=16, T=2048, D=1024] f32
//   mask:   [B, T] bool (arrives as int32 per harness integer convention)
// Outputs flattened into one f32 buffer in return order:
//   collected [B,T,D] f32, valid_idx [B,T] (as float, -1 tail), counts [B] (as float)
//
// R3 post-mortem ledger: 218.8 / 215.8 / 216.2 / 223.7 — all structural
// variants within noise. Model: ~161us harness poison (2x 537MB fills)
// + ~50-55us kernel vs a 34us mandatory-traffic floor. Last untested
// mechanism: NT stores (used in ALL variants) vs the plain write-back
// path that both the 6.7 TB/s poison fill and the 6.29 TB/s copy ubench
// use. This round: R2 structure, plain loads AND plain stores.
// Precommit: |delta| < 4us -> kernel is at its achievable limit, declare
// roofline (residual is harness poison + turnaround).

#define BB 16
#define TT 2048
#define DD 1024
#define ROW4 (DD / 4)    // 256 float4 per row
#define ROWS 16          // output rows per block
#define BPS (TT / ROWS)  // 128 blocks per sample

typedef float f4 __attribute__((ext_vector_type(4)));

__global__ __launch_bounds__(256) void fused_kernel(
    const int* __restrict__ mask,
    const f4* __restrict__ in,      // [B*T][256] f4
    f4* __restrict__ out,           // [B*T][256] f4
    float* __restrict__ out_vidx,   // [B,T] as float
    float* __restrict__ out_counts) // [B]   as float
{
    const int b    = blockIdx.x >> 7;        // 128 blocks per sample
    const int blk  = blockIdx.x & (BPS - 1);
    const int tid  = threadIdx.x;
    const int lane = tid & 63;
    const int wv   = tid >> 6;               // wave 0..3

    // ---- mask load: 8 values/thread (2x int4); row is 8 KB, L2-hot ----
    const int4* m4 = (const int4*)(mask + b * TT);
    int4 a0 = m4[tid * 2];
    int4 a1 = m4[tid * 2 + 1];
    int vals[8];
    vals[0] = (a0.x != 0); vals[1] = (a0.y != 0);
    vals[2] = (a0.z != 0); vals[3] = (a0.w != 0);
    vals[4] = (a1.x != 0); vals[5] = (a1.y != 0);
    vals[6] = (a1.z != 0); vals[7] = (a1.w != 0);
    int s = 0;
#pragma unroll
    for (int i = 0; i < 8; ++i) s += vals[i];

    // ---- block count: wave butterfly reduce + 4-entry combine ----
    int r = s;
#pragma unroll
    for (int off = 1; off < 64; off <<= 1) r += __shfl_xor(r, off, 64);

    __shared__ int wsum[4];
    __shared__ int ssrc[TT];   // compacted source row index, 8 KB
    if (lane == 0) wsum[wv] = r;
    __syncthreads();
    const int cnt = wsum[0] + wsum[1] + wsum[2] + wsum[3];

    const int row0 = blk * ROWS;

    // ---- scan + scatter only when this block owns valid rows (block-uniform) ----
    if (row0 < cnt || blk == 0) {
        int incl = s;
#pragma unroll
        for (int off = 1; off < 64; off <<= 1) {
            int v = __shfl_up(incl, off, 64);
            if (lane >= off) incl += v;
        }
        int woff = 0;
#pragma unroll
        for (int w = 0; w < 4; ++w) woff += (w < wv) ? wsum[w] : 0;
        int pos = woff + incl - s;   // exclusive prefix for this thread
#pragma unroll
        for (int i = 0; i < 8; ++i) {
            if (vals[i]) ssrc[pos++] = tid * 8 + i;
        }
        __syncthreads();
    }

    // ---- one designated block per sample emits valid_idx + counts ----
    if (blk == 0) {
        for (int c = tid; c < TT; c += 256)
            out_vidx[b * TT + c] = (c < cnt) ? (float)ssrc[c] : -1.0f;
        if (tid == 0) out_counts[b] = (float)cnt;
    }

    // ---- gather / zero-fill this block's 16 rows: 2 passes of 8 rows,
    //      32 lanes/row, 8 independent float4 per lane (ILP=8).
    //      Plain cached loads + stores (the 6.29 TB/s copy-ubench idiom). ----
    const int lrow = tid >> 5;   // 0..7 local row within pass
    const int ln   = tid & 31;   // 0..31
#pragma unroll
    for (int p = 0; p < ROWS / 8; ++p) {
        const int c = row0 + p * 8 + lrow;
        f4* dst = out + ((size_t)(b * TT + c)) * ROW4;
        if (c < cnt) {
            const int src = ssrc[c];
            const f4* sp = in + ((size_t)(b * TT + src)) * ROW4;
            f4 v[8];
#pragma unroll
            for (int j = 0; j < 8; ++j)
                v[j] = sp[ln + j * 32];
#pragma unroll
            for (int j = 0; j < 8; ++j)
                dst[ln + j * 32] = v[j];
        } else {
            const f4 z = {0.f, 0.f, 0.f, 0.f};
#pragma unroll
            for (int j = 0; j < 8; ++j)
                dst[ln + j * 32] = z;
        }
    }
}

extern "C" void kernel_launch(void* const* d_in, const int* in_sizes, int n_in,
                              void* d_out, int out_size, void* d_ws, size_t ws_size,
                              hipStream_t stream) {
    const float* inputs = (const float*)d_in[0];
    const int* mask = (const int*)d_in[1];

    float* out = (float*)d_out;
    float* out_collected = out;                       // B*T*D
    float* out_vidx = out + (size_t)BB * TT * DD;     // B*T
    float* out_counts = out_vidx + (size_t)BB * TT;   // B

    fused_kernel<<<BB * BPS, 256, 0, stream>>>(
        mask, (const f4*)inputs, (f4*)out_collected, out_vidx, out_counts);
}

// Round 5
// 215.489 us; speedup vs baseline: 1.0430x; 1.0430x over previous
//
#include <hip/hip_runtime.h>

// PaddedToSegments: batched stream compaction — FUSED single-kernel version.
// REVERT to R1 (best measured: 215.8 us). Ledger: 218.8 / 215.8 / 216.2 /
// 223.7 / 224.8. Cache-mode isolation (R3/R4) showed NT loads+stores beat
// plain cached by ~8 us for this once-through 201 MB stream (NT avoids L2
// write-allocate/pollution while the harness's 2x537 MB poison fills thrash).
//   inputs: [B=16, T=2048, D=1024] f32
//   mask:   [B, T] bool (arrives as int32 per harness integer convention)
// Outputs flattened into one f32 buffer in return order:
//   collected [B,T,D] f32, valid_idx [B,T] (as float, -1 tail), counts [B] (as float)

#define BB 16
#define TT 2048
#define DD 1024
#define ROW4 (DD / 4)   // 256 float4 per row

// Native Clang vector type: accepted by __builtin_nontemporal_* (HIP's float4
// is a class and is rejected).
typedef float f4 __attribute__((ext_vector_type(4)));

__global__ __launch_bounds__(256) void fused_kernel(
    const int* __restrict__ mask,
    const f4* __restrict__ in,      // [B*T][256] f4
    f4* __restrict__ out,           // [B*T][256] f4
    float* __restrict__ out_vidx,   // [B,T] as float
    float* __restrict__ out_counts) // [B]   as float
{
    const int b    = blockIdx.x >> 8;    // 256 blocks per sample
    const int blk  = blockIdx.x & 255;   // block index within sample
    const int tid  = threadIdx.x;
    const int lane = tid & 63;
    const int wv   = tid >> 6;           // wave 0..3

    // ---- per-block mask scan (redundant across the 256 blocks of a sample;
    //      8 KB mask row is L2-resident so HBM cost is paid once per sample) ----
    const int4* m4 = (const int4*)(mask + b * TT);
    int4 a0 = m4[tid * 2];
    int4 a1 = m4[tid * 2 + 1];
    int vals[8];
    vals[0] = (a0.x != 0); vals[1] = (a0.y != 0);
    vals[2] = (a0.z != 0); vals[3] = (a0.w != 0);
    vals[4] = (a1.x != 0); vals[5] = (a1.y != 0);
    vals[6] = (a1.z != 0); vals[7] = (a1.w != 0);
    int s = 0;
#pragma unroll
    for (int i = 0; i < 8; ++i) s += vals[i];

    // Wave-level inclusive scan of per-thread sums (no barriers).
    int incl = s;
#pragma unroll
    for (int off = 1; off < 64; off <<= 1) {
        int v = __shfl_up(incl, off, 64);
        if (lane >= off) incl += v;
    }

    __shared__ int wsum[4];
    __shared__ int ssrc[TT];   // compacted source row index, 8 KB
    if (lane == 63) wsum[wv] = incl;
    __syncthreads();

    int woff = 0;
#pragma unroll
    for (int w = 0; w < 4; ++w) woff += (w < wv) ? wsum[w] : 0;
    const int cnt = wsum[0] + wsum[1] + wsum[2] + wsum[3];

    // Scatter compacted src indices into LDS.
    int pos = woff + incl - s;   // exclusive prefix for this thread
#pragma unroll
    for (int i = 0; i < 8; ++i) {
        if (vals[i]) ssrc[pos++] = tid * 8 + i;
    }
    __syncthreads();

    // ---- one designated block per sample emits valid_idx + counts ----
    if (blk == 0) {
        for (int c = tid; c < TT; c += 256)
            out_vidx[b * TT + c] = (c < cnt) ? (float)ssrc[c] : -1.0f;
        if (tid == 0) out_counts[b] = (float)cnt;
    }

    // ---- gather / zero-fill this block's 8 output rows ----
    // 32 lanes per row, 8 independent float4 loads per lane (ILP=8);
    // non-temporal keeps the ~200 MB stream out of L2's way.
    const int lrow = tid >> 5;              // 0..7 local row
    const int ln   = tid & 31;              // 0..31
    const int c    = blk * 8 + lrow;        // output row within sample
    f4* dst = out + ((size_t)(b * TT + c)) * ROW4;
    if (c < cnt) {
        const int src = ssrc[c];
        const f4* sp = in + ((size_t)(b * TT + src)) * ROW4;
        f4 v[8];
#pragma unroll
        for (int j = 0; j < 8; ++j)
            v[j] = __builtin_nontemporal_load(sp + ln + j * 32);
#pragma unroll
        for (int j = 0; j < 8; ++j)
            __builtin_nontemporal_store(v[j], dst + ln + j * 32);
    } else {
        const f4 z = {0.f, 0.f, 0.f, 0.f};
#pragma unroll
        for (int j = 0; j < 8; ++j)
            __builtin_nontemporal_store(z, dst + ln + j * 32);
    }
}

extern "C" void kernel_launch(void* const* d_in, const int* in_sizes, int n_in,
                              void* d_out, int out_size, void* d_ws, size_t ws_size,
                              hipStream_t stream) {
    const float* inputs = (const float*)d_in[0];
    const int* mask = (const int*)d_in[1];

    float* out = (float*)d_out;
    float* out_collected = out;                       // B*T*D
    float* out_vidx = out + (size_t)BB * TT * DD;     // B*T
    float* out_counts = out_vidx + (size_t)BB * TT;   // B

    fused_kernel<<<BB * 256, 256, 0, stream>>>(
        mask, (const f4*)inputs, (f4*)out_collected, out_vidx, out_counts);
}